// Round 1
// baseline (208.320 us; speedup 1.0000x reference)
//
#include <hip/hip_runtime.h>

// Problem constants (match reference setup_inputs()).
#define Nn 50000
#define Rr 4
#define Dd 5
#define Ee 5000000
#define Bb 4
#define NRr (Nn * Rr)   // 200000
#define NDd (Nn * Dd)   // 250000

// ---------------------------------------------------------------------------
// Kernel 1: pack z_buf (B x N*D floats, values exactly 0.0/1.0) into a
// per-column 4-bit batch mask. 250 KB table -> random gathers in the edge
// kernel hit L1/L2 instead of 4 MB of scattered float loads.
// ---------------------------------------------------------------------------
__global__ void pack_z_kernel(const float* __restrict__ z_buf,
                              unsigned char* __restrict__ z_pack) {
    int i = blockIdx.x * blockDim.x + threadIdx.x;
    if (i >= NDd) return;
    unsigned m = 0;
#pragma unroll
    for (int b = 0; b < Bb; ++b)
        if (z_buf[(size_t)b * NDd + i] != 0.0f) m |= (1u << b);
    z_pack[i] = (unsigned char)m;
}

// ---------------------------------------------------------------------------
// Kernel 2: sparse recurrent input. For each edge e and batch b with a spike
// at rec_cols[e]: i_rec[b][rec_rows[e]] += rec_w[e]. z values are exactly 1.0
// so adding w is exact. ~5% density -> ~1M atomics over 800K addresses.
// Vectorized x4 so the 60 MB of edge data streams as dwordx4 loads.
// ---------------------------------------------------------------------------
__global__ __launch_bounds__(256) void edge_kernel(
    const float4* __restrict__ w4, const int4* __restrict__ rows4,
    const int4* __restrict__ cols4, const unsigned char* __restrict__ z_pack,
    float* __restrict__ i_rec) {
    int i = blockIdx.x * blockDim.x + threadIdx.x;
    if (i >= Ee / 4) return;
    int4 c = cols4[i];
    int4 rw = rows4[i];
    float4 w = w4[i];
    unsigned m0 = z_pack[c.x];
    unsigned m1 = z_pack[c.y];
    unsigned m2 = z_pack[c.z];
    unsigned m3 = z_pack[c.w];
    if ((m0 | m1 | m2 | m3) == 0) return;
#define DO_EDGE(mm, row, wv)                                          \
    if (mm) {                                                         \
        if ((mm) & 1u) atomicAdd(&i_rec[0 * NRr + (row)], (wv));      \
        if ((mm) & 2u) atomicAdd(&i_rec[1 * NRr + (row)], (wv));      \
        if ((mm) & 4u) atomicAdd(&i_rec[2 * NRr + (row)], (wv));      \
        if ((mm) & 8u) atomicAdd(&i_rec[3 * NRr + (row)], (wv));      \
    }
    DO_EDGE(m0, rw.x, w.x)
    DO_EDGE(m1, rw.y, w.y)
    DO_EDGE(m2, rw.z, w.z)
    DO_EDGE(m3, rw.w, w.w)
#undef DO_EDGE
}

// ---------------------------------------------------------------------------
// Kernel 3: elementwise neuron update + output assembly.
// Thread = (batch, neuron). All N*R arrays are float4 per neuron (R=4).
// Output layout per batch (18*N floats):
//   [0,N)=new_z [N,2N)=out_v [2N,3N)=new_r [3N,4N)=asc1 [4N,5N)=asc2
//   [5N,9N)=psc_rise [9N,13N)=psc [13N,18N)=shifted z_buf
// ---------------------------------------------------------------------------
__global__ __launch_bounds__(256) void neuron_kernel(
    const float* __restrict__ inputs, const float* __restrict__ z_buf,
    const float* __restrict__ v_in, const float* __restrict__ r_in,
    const float* __restrict__ asc1_in, const float* __restrict__ asc2_in,
    const float* __restrict__ psc_rise_in, const float* __restrict__ psc_in,
    const float* __restrict__ syn_decay, const float* __restrict__ psc_initial,
    const float* __restrict__ t_ref, const float* __restrict__ asc_amps,
    const float* __restrict__ kparam, const float* __restrict__ v_th,
    const float* __restrict__ e_l, const float* __restrict__ v_reset,
    const float* __restrict__ g, const float* __restrict__ decay,
    const float* __restrict__ current_factor,
    const float* __restrict__ voltage_scale,
    const float* __restrict__ voltage_offset,
    const float* __restrict__ i_rec, float* __restrict__ out) {
    int n = blockIdx.x * blockDim.x + threadIdx.x;
    int b = blockIdx.y;
    if (n >= Nn) return;

    const size_t bn  = (size_t)b * Nn + n;
    const size_t bnr = (size_t)b * NRr + (size_t)n * 4;

    float prev_z = z_buf[(size_t)b * NDd + n];

    float4 ir  = *(const float4*)(i_rec + bnr);
    float4 in4 = *(const float4*)(inputs + bnr);
    float4 pr  = *(const float4*)(psc_rise_in + bnr);
    float4 pc  = *(const float4*)(psc_in + bnr);
    float4 sd  = *(const float4*)(syn_decay + (size_t)n * 4);
    float4 pi  = *(const float4*)(psc_initial + (size_t)n * 4);

    // new_psc_rise = sd*pr + (i_rec+inputs)*pi ; new_psc = pc*sd + sd*pr (DT=1)
    float4 npr, npc;
    npr.x = sd.x * pr.x + (ir.x + in4.x) * pi.x;
    npr.y = sd.y * pr.y + (ir.y + in4.y) * pi.y;
    npr.z = sd.z * pr.z + (ir.z + in4.z) * pi.z;
    npr.w = sd.w * pr.w + (ir.w + in4.w) * pi.w;
    npc.x = pc.x * sd.x + sd.x * pr.x;
    npc.y = pc.y * sd.y + sd.y * pr.y;
    npc.z = pc.z * sd.z + sd.z * pr.z;
    npc.w = pc.w * sd.w + sd.w * pr.w;

    float input_current = pc.x + pc.y + pc.z + pc.w;   // OLD psc

    float tr    = t_ref[n];
    float new_r = fmaxf(r_in[bn] + prev_z * tr - 1.0f, 0.0f);

    float2 kv = *(const float2*)(kparam + (size_t)n * 2);
    float2 aa = *(const float2*)(asc_amps + (size_t)n * 2);
    float kk0 = 1.0f / (1.0f + expf(-kv.x));
    float kk1 = 1.0f / (1.0f + expf(-kv.y));
    float a1 = asc1_in[bn];
    float a2 = asc2_in[bn];
    float na1 = expf(-kk0) * a1 + prev_z * aa.x;
    float na2 = expf(-kk1) * a2 + prev_z * aa.y;

    float vth = v_th[n];
    float el  = e_l[n];
    float reset_current = prev_z * (v_reset[n] - vth);
    float c1 = input_current + a1 + a2 + g[n] * el;    // OLD asc values
    float new_v = decay[n] * v_in[bn] + current_factor[n] * c1 + reset_current;

    float v_sc = (new_v - vth) / (vth - el);
    float new_z = (v_sc > 0.0f) ? 1.0f : 0.0f;
    if (new_r > 0.0f) new_z = 0.0f;

    float out_v = new_v * voltage_scale[n] + voltage_offset[n];

    float* ob = out + (size_t)b * 18 * Nn;
    ob[n]            = new_z;
    ob[Nn + n]       = out_v;
    ob[2 * Nn + n]   = new_r;
    ob[3 * Nn + n]   = na1;
    ob[4 * Nn + n]   = na2;
    *(float4*)(ob + 5 * Nn + (size_t)n * 4) = npr;
    *(float4*)(ob + 9 * Nn + (size_t)n * 4) = npc;
    // new_z_buf: slot 0 = new_z, slots 1..D-1 = old slots 0..D-2
    ob[13 * Nn + n] = new_z;
#pragma unroll
    for (int d = 0; d < Dd - 1; ++d)
        ob[14 * Nn + (size_t)d * Nn + n] = z_buf[(size_t)b * NDd + (size_t)d * Nn + n];
}

extern "C" void kernel_launch(void* const* d_in, const int* in_sizes, int n_in,
                              void* d_out, int out_size, void* d_ws, size_t ws_size,
                              hipStream_t stream) {
    const float* inputs        = (const float*)d_in[0];
    const float* z_buf         = (const float*)d_in[1];
    const float* v             = (const float*)d_in[2];
    const float* r             = (const float*)d_in[3];
    const float* asc_1         = (const float*)d_in[4];
    const float* asc_2         = (const float*)d_in[5];
    const float* psc_rise      = (const float*)d_in[6];
    const float* psc           = (const float*)d_in[7];
    const float* rec_w         = (const float*)d_in[8];
    const int*   rec_rows      = (const int*)d_in[9];
    const int*   rec_cols      = (const int*)d_in[10];
    const float* syn_decay     = (const float*)d_in[11];
    const float* psc_initial   = (const float*)d_in[12];
    const float* t_ref         = (const float*)d_in[13];
    const float* asc_amps      = (const float*)d_in[14];
    const float* k             = (const float*)d_in[15];
    const float* v_th          = (const float*)d_in[16];
    const float* e_l           = (const float*)d_in[17];
    const float* v_reset       = (const float*)d_in[18];
    const float* g             = (const float*)d_in[19];
    const float* decay         = (const float*)d_in[20];
    const float* current_factor= (const float*)d_in[21];
    const float* voltage_scale = (const float*)d_in[22];
    const float* voltage_offset= (const float*)d_in[23];
    float* out = (float*)d_out;

    // Workspace: i_rec accumulator (B*N*R floats), then z_pack (N*D bytes).
    float* i_rec = (float*)d_ws;
    unsigned char* z_pack = (unsigned char*)d_ws + (size_t)Bb * NRr * sizeof(float);

    hipMemsetAsync(i_rec, 0, (size_t)Bb * NRr * sizeof(float), stream);

    pack_z_kernel<<<(NDd + 255) / 256, 256, 0, stream>>>(z_buf, z_pack);

    edge_kernel<<<(Ee / 4 + 255) / 256, 256, 0, stream>>>(
        (const float4*)rec_w, (const int4*)rec_rows, (const int4*)rec_cols,
        z_pack, i_rec);

    dim3 ngrid((Nn + 255) / 256, Bb);
    neuron_kernel<<<ngrid, 256, 0, stream>>>(
        inputs, z_buf, v, r, asc_1, asc_2, psc_rise, psc,
        syn_decay, psc_initial, t_ref, asc_amps, k, v_th, e_l, v_reset,
        g, decay, current_factor, voltage_scale, voltage_offset,
        i_rec, out);
}

// Round 2
// 204.841 us; speedup vs baseline: 1.0170x; 1.0170x over previous
//
#include <hip/hip_runtime.h>

// Problem constants (match reference setup_inputs()).
#define Nn 50000
#define Rr 4
#define Dd 5
#define Ee 5000000
#define Bb 4
#define NRr (Nn * Rr)   // 200000
#define NDd (Nn * Dd)   // 250000
#define ZW 7814         // ceil(250000/32)=7813 (+1 guard word for the ballot hi-write)

// ---------------------------------------------------------------------------
// Kernel 1: zero i_rec + pack z_buf into (a) per-column 4-bit batch mask bytes
// (z_pack, 250 KB, global) and (b) a 1-bit-per-column OR-over-batches mask
// (zbits, 31.3 KB) that the edge kernel stages into LDS. 95% of columns have
// no spike in ANY batch (0.95^4 = 81.5% here), so the LDS bit kills most of
// the scattered global gathers.
// ---------------------------------------------------------------------------
__global__ __launch_bounds__(256) void pack_z_kernel(
    const float* __restrict__ z_buf, unsigned char* __restrict__ z_pack,
    unsigned* __restrict__ zbits, float4* __restrict__ i_rec4) {
    int i = blockIdx.x * 256 + threadIdx.x;
    // Zero the accumulator (B*N*R floats = 200000 float4 <= grid threads).
    if (i < Bb * NRr / 4) i_rec4[i] = make_float4(0.f, 0.f, 0.f, 0.f);
    unsigned m = 0;
    if (i < NDd) {
#pragma unroll
        for (int b = 0; b < Bb; ++b)
            if (z_buf[(size_t)b * NDd + i] != 0.0f) m |= (1u << b);
        z_pack[i] = (unsigned char)m;
    }
    // Wave-wide bit pack: 64 consecutive columns -> two u32 words.
    unsigned long long bal = __ballot(m != 0);
    if ((i & 63) == 0 && i < NDd) {
        zbits[(i >> 5)]     = (unsigned)bal;
        zbits[(i >> 5) + 1] = (unsigned)(bal >> 32);
    }
}

// ---------------------------------------------------------------------------
// Kernel 2: sparse recurrent input. LDS-staged 1-bit column mask filters the
// 20M (edge,batch) pairs down to ~18.5% of columns before any scattered
// global access; full batch mask byte is fetched only on hit. Atomic adds of
// w (z is exactly 1.0, so the sums are exact modulo ordering).
// ---------------------------------------------------------------------------
__global__ __launch_bounds__(256) void edge_kernel(
    const float4* __restrict__ w4, const int4* __restrict__ rows4,
    const int4* __restrict__ cols4, const unsigned char* __restrict__ z_pack,
    const unsigned* __restrict__ zbits, float* __restrict__ i_rec) {
    __shared__ unsigned zb[ZW];
    for (int t = threadIdx.x; t < ZW; t += 256) zb[t] = zbits[t];
    __syncthreads();
    const int nq = Ee / 4;
    for (int i = blockIdx.x * 256 + threadIdx.x; i < nq;
         i += gridDim.x * 256) {
        int4 c = cols4[i];
        unsigned h0 = (zb[(unsigned)c.x >> 5] >> (c.x & 31)) & 1u;
        unsigned h1 = (zb[(unsigned)c.y >> 5] >> (c.y & 31)) & 1u;
        unsigned h2 = (zb[(unsigned)c.z >> 5] >> (c.z & 31)) & 1u;
        unsigned h3 = (zb[(unsigned)c.w >> 5] >> (c.w & 31)) & 1u;
        if (!(h0 | h1 | h2 | h3)) continue;
        int4 rw = rows4[i];
        float4 w = w4[i];
#define DO_EDGE(hh, col, row, wv)                                     \
    if (hh) {                                                         \
        unsigned mm = z_pack[col];                                    \
        if (mm & 1u) atomicAdd(&i_rec[0 * NRr + (row)], (wv));        \
        if (mm & 2u) atomicAdd(&i_rec[1 * NRr + (row)], (wv));        \
        if (mm & 4u) atomicAdd(&i_rec[2 * NRr + (row)], (wv));        \
        if (mm & 8u) atomicAdd(&i_rec[3 * NRr + (row)], (wv));        \
    }
        DO_EDGE(h0, c.x, rw.x, w.x)
        DO_EDGE(h1, c.y, rw.y, w.y)
        DO_EDGE(h2, c.z, rw.z, w.z)
        DO_EDGE(h3, c.w, rw.w, w.w)
#undef DO_EDGE
    }
}

// ---------------------------------------------------------------------------
// Kernel 3: elementwise neuron update + output assembly.
// Thread = (batch, neuron). All N*R arrays are float4 per neuron (R=4).
// Output layout per batch (18*N floats):
//   [0,N)=new_z [N,2N)=out_v [2N,3N)=new_r [3N,4N)=asc1 [4N,5N)=asc2
//   [5N,9N)=psc_rise [9N,13N)=psc [13N,18N)=shifted z_buf
// ---------------------------------------------------------------------------
__global__ __launch_bounds__(256) void neuron_kernel(
    const float* __restrict__ inputs, const float* __restrict__ z_buf,
    const float* __restrict__ v_in, const float* __restrict__ r_in,
    const float* __restrict__ asc1_in, const float* __restrict__ asc2_in,
    const float* __restrict__ psc_rise_in, const float* __restrict__ psc_in,
    const float* __restrict__ syn_decay, const float* __restrict__ psc_initial,
    const float* __restrict__ t_ref, const float* __restrict__ asc_amps,
    const float* __restrict__ kparam, const float* __restrict__ v_th,
    const float* __restrict__ e_l, const float* __restrict__ v_reset,
    const float* __restrict__ g, const float* __restrict__ decay,
    const float* __restrict__ current_factor,
    const float* __restrict__ voltage_scale,
    const float* __restrict__ voltage_offset,
    const float* __restrict__ i_rec, float* __restrict__ out) {
    int n = blockIdx.x * blockDim.x + threadIdx.x;
    int b = blockIdx.y;
    if (n >= Nn) return;

    const size_t bn  = (size_t)b * Nn + n;
    const size_t bnr = (size_t)b * NRr + (size_t)n * 4;

    float prev_z = z_buf[(size_t)b * NDd + n];

    float4 ir  = *(const float4*)(i_rec + bnr);
    float4 in4 = *(const float4*)(inputs + bnr);
    float4 pr  = *(const float4*)(psc_rise_in + bnr);
    float4 pc  = *(const float4*)(psc_in + bnr);
    float4 sd  = *(const float4*)(syn_decay + (size_t)n * 4);
    float4 pi  = *(const float4*)(psc_initial + (size_t)n * 4);

    // new_psc_rise = sd*pr + (i_rec+inputs)*pi ; new_psc = pc*sd + sd*pr (DT=1)
    float4 npr, npc;
    npr.x = sd.x * pr.x + (ir.x + in4.x) * pi.x;
    npr.y = sd.y * pr.y + (ir.y + in4.y) * pi.y;
    npr.z = sd.z * pr.z + (ir.z + in4.z) * pi.z;
    npr.w = sd.w * pr.w + (ir.w + in4.w) * pi.w;
    npc.x = pc.x * sd.x + sd.x * pr.x;
    npc.y = pc.y * sd.y + sd.y * pr.y;
    npc.z = pc.z * sd.z + sd.z * pr.z;
    npc.w = pc.w * sd.w + sd.w * pr.w;

    float input_current = pc.x + pc.y + pc.z + pc.w;   // OLD psc

    float tr    = t_ref[n];
    float new_r = fmaxf(r_in[bn] + prev_z * tr - 1.0f, 0.0f);

    float2 kv = *(const float2*)(kparam + (size_t)n * 2);
    float2 aa = *(const float2*)(asc_amps + (size_t)n * 2);
    float kk0 = 1.0f / (1.0f + expf(-kv.x));
    float kk1 = 1.0f / (1.0f + expf(-kv.y));
    float a1 = asc1_in[bn];
    float a2 = asc2_in[bn];
    float na1 = expf(-kk0) * a1 + prev_z * aa.x;
    float na2 = expf(-kk1) * a2 + prev_z * aa.y;

    float vth = v_th[n];
    float el  = e_l[n];
    float reset_current = prev_z * (v_reset[n] - vth);
    float c1 = input_current + a1 + a2 + g[n] * el;    // OLD asc values
    float new_v = decay[n] * v_in[bn] + current_factor[n] * c1 + reset_current;

    float v_sc = (new_v - vth) / (vth - el);
    float new_z = (v_sc > 0.0f) ? 1.0f : 0.0f;
    if (new_r > 0.0f) new_z = 0.0f;

    float out_v = new_v * voltage_scale[n] + voltage_offset[n];

    float* ob = out + (size_t)b * 18 * Nn;
    ob[n]            = new_z;
    ob[Nn + n]       = out_v;
    ob[2 * Nn + n]   = new_r;
    ob[3 * Nn + n]   = na1;
    ob[4 * Nn + n]   = na2;
    *(float4*)(ob + 5 * Nn + (size_t)n * 4) = npr;
    *(float4*)(ob + 9 * Nn + (size_t)n * 4) = npc;
    // new_z_buf: slot 0 = new_z, slots 1..D-1 = old slots 0..D-2
    ob[13 * Nn + n] = new_z;
#pragma unroll
    for (int d = 0; d < Dd - 1; ++d)
        ob[14 * Nn + (size_t)d * Nn + n] = z_buf[(size_t)b * NDd + (size_t)d * Nn + n];
}

extern "C" void kernel_launch(void* const* d_in, const int* in_sizes, int n_in,
                              void* d_out, int out_size, void* d_ws, size_t ws_size,
                              hipStream_t stream) {
    const float* inputs        = (const float*)d_in[0];
    const float* z_buf         = (const float*)d_in[1];
    const float* v             = (const float*)d_in[2];
    const float* r             = (const float*)d_in[3];
    const float* asc_1         = (const float*)d_in[4];
    const float* asc_2         = (const float*)d_in[5];
    const float* psc_rise      = (const float*)d_in[6];
    const float* psc           = (const float*)d_in[7];
    const float* rec_w         = (const float*)d_in[8];
    const int*   rec_rows      = (const int*)d_in[9];
    const int*   rec_cols      = (const int*)d_in[10];
    const float* syn_decay     = (const float*)d_in[11];
    const float* psc_initial   = (const float*)d_in[12];
    const float* t_ref         = (const float*)d_in[13];
    const float* asc_amps      = (const float*)d_in[14];
    const float* k             = (const float*)d_in[15];
    const float* v_th          = (const float*)d_in[16];
    const float* e_l           = (const float*)d_in[17];
    const float* v_reset       = (const float*)d_in[18];
    const float* g             = (const float*)d_in[19];
    const float* decay         = (const float*)d_in[20];
    const float* current_factor= (const float*)d_in[21];
    const float* voltage_scale = (const float*)d_in[22];
    const float* voltage_offset= (const float*)d_in[23];
    float* out = (float*)d_out;

    // Workspace layout: i_rec floats [B*N*R] | z_pack bytes [N*D] | zbits u32 [ZW]
    float* i_rec = (float*)d_ws;
    unsigned char* z_pack = (unsigned char*)d_ws + (size_t)Bb * NRr * sizeof(float);
    unsigned* zbits = (unsigned*)(z_pack + ((NDd + 255) & ~255));

    pack_z_kernel<<<(NDd + 255) / 256, 256, 0, stream>>>(
        z_buf, z_pack, zbits, (float4*)i_rec);

    edge_kernel<<<2048, 256, 0, stream>>>(
        (const float4*)rec_w, (const int4*)rec_rows, (const int4*)rec_cols,
        z_pack, zbits, i_rec);

    dim3 ngrid((Nn + 255) / 256, Bb);
    neuron_kernel<<<ngrid, 256, 0, stream>>>(
        inputs, z_buf, v, r, asc_1, asc_2, psc_rise, psc,
        syn_decay, psc_initial, t_ref, asc_amps, k, v_th, e_l, v_reset,
        g, decay, current_factor, voltage_scale, voltage_offset,
        i_rec, out);
}